// Round 6
// baseline (230.860 us; speedup 1.0000x reference)
//
#include <hip/hip_runtime.h>

#define B_ 16
#define C_ 256
#define N_ 16384      // 128*128
#define R_ 16
#define SUB_ 32       // n per subtile staged in LDS
#define LSTR_ 33      // 32+1 pad: all LDS phases <=2-way bank aliasing (free)

typedef float f32x4 __attribute__((ext_vector_type(4)));

// ---------------------------------------------------------------------------
// kA: fused stats pass, software-pipelined.
// Per 32-n subtile: stage x[b, 0:256, n0:n0+32] in LDS row-major [c][33],
// colsum[n] = sum_c tile[c][n]; accP[c] += x*colsum; accRS[c] += x.
// Next subtile's global loads are issued into registers BEFORE the compute
// phases, so HBM stays busy across the barriers (T14 issue-early pattern).
// LDS ~34 KiB -> 4 blocks/CU -> 16 waves/CU.
// ---------------------------------------------------------------------------
template<int NSUB>
__global__ __launch_bounds__(256, 4)
void kA(const float* __restrict__ x,
        float* __restrict__ Ppart,
        float* __restrict__ RSpart,
        int blocksPerBatch) {
    const int blk = blockIdx.x;
    const int b = blockIdx.y;
    const int t = threadIdx.x;

    __shared__ float tile[C_][LSTR_];     // [c][n], padded
    __shared__ float csum_part[8][32];
    __shared__ float colsum[SUB_];

    const int nbase = blk * (NSUB * SUB_);
    const int kq = t & 7;      // float4 slot within the 32-n row (0..7)
    const int crow = t >> 3;   // base channel row (0..31)

    const float* xb = x + (size_t)b * C_ * N_ + nbase + (kq << 2);

    float4 pre[8];
#pragma unroll
    for (int r = 0; r < 8; ++r)
        pre[r] = *reinterpret_cast<const float4*>(xb + (size_t)(crow + (r << 5)) * N_);

    float accP = 0.f, accRS = 0.f;

    for (int s = 0; s < NSUB; ++s) {
        // ---- stage subtile s from regs (8 x ds_write_b128)
#pragma unroll
        for (int r = 0; r < 8; ++r)
            *reinterpret_cast<float4*>(&tile[crow + (r << 5)][kq << 2]) = pre[r];
        // ---- issue subtile s+1 loads NOW (in flight during compute below)
        if (s + 1 < NSUB) {
#pragma unroll
            for (int r = 0; r < 8; ++r)
                pre[r] = *reinterpret_cast<const float4*>(
                    xb + (size_t)(crow + (r << 5)) * N_ + (s + 1) * SUB_);
        }
        __syncthreads();
        // ---- colsum partials: thread (n = t&31, oct = t>>5) sums 32 channels
        {
            const int n = t & 31, oct = t >> 5;
            float cs = 0.f;
#pragma unroll
            for (int i = 0; i < 32; ++i) cs += tile[(oct << 5) + i][n];
            csum_part[oct][n] = cs;
        }
        __syncthreads();
        if (t < SUB_) {
            float cs = 0.f;
#pragma unroll
            for (int o = 0; o < 8; ++o) cs += csum_part[o][t];
            colsum[t] = cs;
        }
        __syncthreads();
        // ---- P / RS accumulation: thread owns channel c = t
#pragma unroll
        for (int n = 0; n < SUB_; ++n) {
            const float tv = tile[t][n];
            accP += tv * colsum[n];
            accRS += tv;
        }
        __syncthreads();   // tile reused next subtile
    }
    Ppart [((size_t)b * blocksPerBatch + blk) * C_ + t] = accP;
    RSpart[((size_t)b * blocksPerBatch + blk) * C_ + t] = accRS;
}

// ---------------------------------------------------------------------------
// kB: reduce partials -> v -> fused MLP -> gate.  grid(B_) x 256, thread = c.
// ---------------------------------------------------------------------------
__global__ void kB(const float* __restrict__ Ppart,
                   const float* __restrict__ RSpart,
                   const float* __restrict__ w1, const float* __restrict__ b1,
                   const float* __restrict__ w2, const float* __restrict__ b2,
                   float* __restrict__ gate, int blocksPerBatch) {
    const int b = blockIdx.x;
    const int t = threadIdx.x;   // channel c

    float P = 0.f, RS = 0.f;
    for (int k = 0; k < blocksPerBatch; ++k) {
        P  += Ppart [((size_t)b * blocksPerBatch + k) * C_ + t];
        RS += RSpart[((size_t)b * blocksPerBatch + k) * C_ + t];
    }

    __shared__ float red[4];
    float s = RS;
#pragma unroll
    for (int off = 32; off; off >>= 1) s += __shfl_down(s, off, 64);
    if ((t & 63) == 0) red[t >> 6] = s;
    __syncthreads();
    const float T = red[0] + red[1] + red[2] + red[3];
    const float M = T / (float)N_;
    const float denom = (float)(N_ - 1) * (float)C_;

    __shared__ float vl[C_];
    vl[t] = (P - M * RS) / denom;
    __syncthreads();

    __shared__ float hpart[R_][16];
    __shared__ float h1[R_];
    {
        const int i = t >> 4, cc = t & 15;
        float a = 0.f;
#pragma unroll
        for (int k = 0; k < 16; ++k)
            a += vl[(cc << 4) + k] * w1[i * C_ + (cc << 4) + k];
        hpart[i][cc] = a;
    }
    __syncthreads();
    if (t < R_) {
        float a = b1[t];
#pragma unroll
        for (int k = 0; k < 16; ++k) a += hpart[t][k];
        h1[t] = a > 0.f ? a : 0.f;
    }
    __syncthreads();

    float a = b2[t];
#pragma unroll
    for (int i = 0; i < R_; ++i) a += h1[i] * w2[t * R_ + i];
    gate[b * C_ + t] = 1.f / (1.f + __expf(-a));
}

// ---------------------------------------------------------------------------
// kC: out = x * gate[b,c].  x read normally (L3 hits from kA's warm);
// out written non-temporally (nt -> LLC no-allocate) so x stays resident.
// ---------------------------------------------------------------------------
__global__ void kC(const float* __restrict__ x,
                   const float* __restrict__ gate,
                   float* __restrict__ out) {
    const size_t total4 = (size_t)B_ * C_ * N_ / 4;
    for (size_t i = (size_t)blockIdx.x * blockDim.x + threadIdx.x; i < total4;
         i += (size_t)gridDim.x * blockDim.x) {
        const int bc = (int)(i >> 12);           // N_/4 = 4096 float4 per (b,c)
        const float g = gate[bc];
        float4 vx = reinterpret_cast<const float4*>(x)[i];
        f32x4 r;
        r.x = vx.x * g; r.y = vx.y * g; r.z = vx.z * g; r.w = vx.w * g;
        __builtin_nontemporal_store(r, reinterpret_cast<f32x4*>(out) + i);
    }
}

extern "C" void kernel_launch(void* const* d_in, const int* in_sizes, int n_in,
                              void* d_out, int out_size, void* d_ws, size_t ws_size,
                              hipStream_t stream) {
    (void)in_sizes; (void)n_in; (void)out_size;
    const float* x  = (const float*)d_in[0];
    const float* w1 = (const float*)d_in[1];
    const float* b1 = (const float*)d_in[2];
    const float* w2 = (const float*)d_in[3];
    const float* b2 = (const float*)d_in[4];
    float* out = (float*)d_out;

    const size_t need64 = (size_t)(2 * B_ * 64 * C_ + B_ * C_) * sizeof(float);
    const int bpb = (ws_size >= need64) ? 64 : 32;   // blocks per batch

    float* ws     = (float*)d_ws;
    float* Ppart  = ws;                                    // B_*bpb*C_
    float* RSpart = Ppart + (size_t)B_ * bpb * C_;         // B_*bpb*C_
    float* gate   = RSpart + (size_t)B_ * bpb * C_;        // B_*C_

    if (bpb == 64) {
        hipLaunchKernelGGL((kA<8>), dim3(64, B_), dim3(256), 0, stream,
                           x, Ppart, RSpart, 64);
    } else {
        hipLaunchKernelGGL((kA<16>), dim3(32, B_), dim3(256), 0, stream,
                           x, Ppart, RSpart, 32);
    }
    hipLaunchKernelGGL(kB, dim3(B_), dim3(256), 0, stream,
                       Ppart, RSpart, w1, b1, w2, b2, gate, bpb);
    hipLaunchKernelGGL(kC, dim3(2048), dim3(256), 0, stream,
                       x, gate, out);
}